// Round 12
// baseline (175.441 us; speedup 1.0000x reference)
//
#include <hip/hip_runtime.h>
#include <cstdint>
#include <cstddef>

static constexpr int Gn = 2;
static constexpr int Tn = 4096;
static constexpr int Hn = 2048;
static constexpr int En = 64;
static constexpr int CAPn = 128;
static constexpr size_t GT = (size_t)Gn * Tn;          // 8192
static constexpr size_t GTEC = GT * En * CAPn;         // 67,108,864
static constexpr size_t GTEC4 = GTEC / 4;              // float4 units

typedef float  f4v __attribute__((ext_vector_type(4)));  // NT-store vec
typedef double d4v __attribute__((ext_vector_type(4)));  // MFMA f64 acc

// ---------------------------------------------------------------------------
// Wave-level (64 lanes = 64 experts) softmax + top-2 + z-loss term, all f64.
// Returns p (this lane's expert probability) for the caller's aux-loss sum.
// Tie-breaking on equal probs: lower expert index wins (matches lax.top_k).
// ---------------------------------------------------------------------------
__device__ inline double wave_softmax_topk(
    double logit, int g, int t,
    double* __restrict__ dkey, double* __restrict__ dlogz2,
    int* __restrict__ idx0, int* __restrict__ idx1,
    float* __restrict__ g0f, float* __restrict__ g1f)
{
  const int e = threadIdx.x & 63;
  double m = logit;
  #pragma unroll
  for (int off = 32; off; off >>= 1) {
    double o = __shfl_xor(m, off);
    m = o > m ? o : m;
  }
  double ex = exp(logit - m);
  double s = ex;
  #pragma unroll
  for (int off = 32; off; off >>= 1) s += __shfl_xor(s, off);
  double p = ex / s;
  size_t gt = (size_t)g * Tn + t;

  // top-1 (value, index) with lower-index tie-break
  double bp = p; int bi = e;
  #pragma unroll
  for (int off = 32; off; off >>= 1) {
    double op = __shfl_xor(bp, off);
    int    oi = __shfl_xor(bi, off);
    if (op > bp || (op == bp && oi < bi)) { bp = op; bi = oi; }
  }
  // top-2: mask out top-1 lane
  double q = (e == bi) ? -1.0 : p;
  double bp2 = q; int bi2 = e;
  #pragma unroll
  for (int off = 32; off; off >>= 1) {
    double op = __shfl_xor(bp2, off);
    int    oi = __shfl_xor(bi2, off);
    if (op > bp2 || (op == bp2 && oi < bi2)) { bp2 = op; bi2 = oi; }
  }
  if (e == 0) {
    dkey[gt] = bp;                       // sort key = top-1 gate (f64)
    double lz = m + log(s);              // logsumexp
    dlogz2[gt] = lz * lz;
    idx0[gt] = bi;  idx1[gt] = bi2;
    g0f[gt] = (float)bp;  g1f[gt] = (float)bp2;
  }
  return p;
}

// ---------------------------------------------------------------------------
// k0_probe: empirically determine the f64 MFMA D-fragment layout.
// Probe 1: A[i][k]=i, B=1  => D[i][j] = 4i  -> rowmap[lane][r] = 4*row.
// Probe 2: A=1, B[k][j]=j  => D[i][j] = 4j  -> colmap[lane][r] = 4*col.
// Integer-exact in f64; makes k1 correct under ANY D permutation.
// ---------------------------------------------------------------------------
__global__ __launch_bounds__(64) void k0_probe(
    double* __restrict__ rowmap, double* __restrict__ colmap)
{
  const int lane = threadIdx.x & 63;
  const double ai = (double)(lane & 15);
  d4v accR = {0., 0., 0., 0.};
  d4v accC = {0., 0., 0., 0.};
  accR = __builtin_amdgcn_mfma_f64_16x16x4f64(ai, 1.0, accR, 0, 0, 0);
  accC = __builtin_amdgcn_mfma_f64_16x16x4f64(1.0, ai, accC, 0, 0, 0);
  #pragma unroll
  for (int r = 0; r < 4; ++r) {
    rowmap[lane * 4 + r] = accR[r];
    colmap[lane * 4 + r] = accC[r];
  }
}

// ---------------------------------------------------------------------------
// k1 v11: ROLE-SPLIT waves. 512 blocks x 512 threads (2 blocks/CU).
// Waves 0-3: COMPUTE ONLY — f64-MFMA logits, wave w owns H-quarter w
//   (512 h = 128 K-steps), 1-deep register prefetch. Their vmcnt traffic
//   is loads only -> load waits never serialize behind store drain.
// Waves 4-7: ZERO-FILL ONLY — block's 1 MiB output slabs via 256 coalesced
//   NT float4 stores per lane. They saturate HBM write BW while compute
//   waves run the MFMA pipe underneath (no shared vmcnt with compute).
// A: lane=16k+i holds X[t0+i][h0+k]; B: lane=16k+j holds W[h0+k][e0+j];
// D scattered via probe-derived rowm/colm. H-quarters summed in fixed
// order via LDS (f64 reorder-safe; structure identical to passing R10/R11).
// ---------------------------------------------------------------------------
__global__ __launch_bounds__(512, 4) void k1_gemm(
    const float* __restrict__ X, const float* __restrict__ W,
    const float* __restrict__ Bv,
    const double* __restrict__ rowmap, const double* __restrict__ colmap,
    double* __restrict__ dkey, double* __restrict__ dlogz2,
    int* __restrict__ idx0, int* __restrict__ idx1,
    float* __restrict__ g0f, float* __restrict__ g1f,
    double* __restrict__ partial, float* __restrict__ out)
{
  __shared__ double lred[4][16][64];               // 32 KB partial logits
  __shared__ double pred[4][64];                   // 2 KB psum partials
  const int tid  = threadIdx.x;
  const int lane = tid & 63;
  const int w    = tid >> 6;                       // 0..7
  const int bid  = blockIdx.x;
  const int g    = bid >> 8;                       // 256 blocks per group
  const int tb   = (bid & 255) * 16;               // block's first token
  const size_t gt0 = (size_t)g * Tn + tb;

  if (w >= 4) {
    // -------- fill waves: 65536 float4 zeros across both output slabs ----
    const int fl = (w - 4) * 64 + lane;            // 0..255
    f4v* __restrict__ ob = (f4v*)out;
    const f4v zf = {0.f, 0.f, 0.f, 0.f};
    #pragma unroll 4
    for (int it = 0; it < 256; ++it) {
      int n = it * 256 + fl;                       // [0, 65536)
      size_t i1 = (size_t)(n >> 15) * GTEC4 + gt0 * 2048 + (n & 32767);
      __builtin_nontemporal_store(zf, &ob[i1]);
    }
    __syncthreads();                               // match compute waves
    __syncthreads();
    return;
  }

  // ---------- compute waves: H-quarter w, 128 K-steps, prefetch d1 -------
  const int tl = lane & 15;                        // i (A-row) / j (B-col)
  const int kl = lane >> 4;                        // k within K=4

  int rowm[4], colm[4];
  #pragma unroll
  for (int r = 0; r < 4; ++r) {
    rowm[r] = (int)(rowmap[lane * 4 + r] * 0.25 + 0.5);
    colm[r] = (int)(colmap[lane * 4 + r] * 0.25 + 0.5);
  }

  const float* __restrict__ xa = X + (gt0 + tl) * Hn + w * 512 + kl;
  const float* __restrict__ wb = W + (size_t)(w * 512 + kl) * En + tl;

  d4v acc0 = {0., 0., 0., 0.};
  d4v acc1 = {0., 0., 0., 0.};
  d4v acc2 = {0., 0., 0., 0.};
  d4v acc3 = {0., 0., 0., 0.};

  // prologue: load step 0
  float a_n = xa[0];
  const float* wr0 = wb;
  float w0_n = wr0[0], w1_n = wr0[16], w2_n = wr0[32], w3_n = wr0[48];

  for (int k4 = 0; k4 < 128; ++k4) {
    double a  = (double)a_n;
    double b0 = (double)w0_n;
    double b1 = (double)w1_n;
    double b2 = (double)w2_n;
    double b3 = (double)w3_n;
    if (k4 < 127) {                                // prefetch next step
      a_n = xa[4 * (k4 + 1)];
      const float* wr = wb + (size_t)(4 * (k4 + 1)) * En;
      w0_n = wr[0]; w1_n = wr[16]; w2_n = wr[32]; w3_n = wr[48];
    }
    acc0 = __builtin_amdgcn_mfma_f64_16x16x4f64(a, b0, acc0, 0, 0, 0);
    acc1 = __builtin_amdgcn_mfma_f64_16x16x4f64(a, b1, acc1, 0, 0, 0);
    acc2 = __builtin_amdgcn_mfma_f64_16x16x4f64(a, b2, acc2, 0, 0, 0);
    acc3 = __builtin_amdgcn_mfma_f64_16x16x4f64(a, b3, acc3, 0, 0, 0);
  }

  // D[rowm[r]][colm[r] + 16*et] -> lred[w][token][expert] (probe-corrected)
  #pragma unroll
  for (int r = 0; r < 4; ++r) {
    lred[w][rowm[r]][colm[r]]      = acc0[r];
    lred[w][rowm[r]][16 + colm[r]] = acc1[r];
    lred[w][rowm[r]][32 + colm[r]] = acc2[r];
    lred[w][rowm[r]][48 + colm[r]] = acc3[r];
  }
  __syncthreads();

  // softmax/top2: wave w handles tokens 4w..4w+3; lane = expert.
  const double bv = (double)Bv[lane];
  double psum = 0.0;
  #pragma unroll
  for (int j = 0; j < 4; ++j) {
    int t = w * 4 + j;
    double full = lred[0][t][lane] + lred[1][t][lane]
                + lred[2][t][lane] + lred[3][t][lane] + bv;
    psum += wave_softmax_topk(full, g, tb + t,
                              dkey, dlogz2, idx0, idx1, g0f, g1f);
  }
  pred[w][lane] = psum;
  __syncthreads();
  if (tid < 64) {
    partial[(size_t)bid * 64 + tid] =
        pred[0][tid] + pred[1][tid] + pred[2][tid] + pred[3][tid];
  }
}

// ---------------------------------------------------------------------------
// k2: stable descending rank, parallelized. 256 blocks; each block ranks
// 32 tokens against all Tn keys (staged once in LDS); 8 threads per token
// each scan 512 keys via b128 reads; integer partials summed exactly.
// ---------------------------------------------------------------------------
__global__ __launch_bounds__(256) void k2_rank(
    const double* __restrict__ dkey,
    const int* __restrict__ idx0, const int* __restrict__ idx1,
    int* __restrict__ perm, int* __restrict__ sidx0, int* __restrict__ sidx1)
{
  __shared__ __align__(16) double keys[Tn];        // 32 KB
  __shared__ int rk[32][8];
  const int tid = threadIdx.x;
  const int bid = blockIdx.x;
  const int g    = bid >> 7;                       // 128 blocks per group
  const int part = bid & 127;                      // 32 tokens per block
  const size_t gbase = (size_t)g * Tn;
  for (int i = tid; i < Tn; i += 256) keys[i] = dkey[gbase + i];
  __syncthreads();

  const int tl = tid >> 3;                         // token-local 0..31
  const int q  = tid & 7;                          // scan segment 0..7
  const int tg = part * 32 + tl;
  const double k = keys[tg];
  int r = 0;
  #pragma unroll 4
  for (int j2 = q * 512; j2 < q * 512 + 512; j2 += 2) {
    double2 kj = *(const double2*)&keys[j2];
    r += (kj.x > k) || (kj.x == k && (j2     < tg));
    r += (kj.y > k) || (kj.y == k && (j2 + 1 < tg));
  }
  rk[tl][q] = r;
  __syncthreads();
  if (tid < 32) {
    const int tg2 = part * 32 + tid;
    int rr = 0;
    #pragma unroll
    for (int u = 0; u < 8; ++u) rr += rk[tid][u];
    perm[gbase + rr]  = tg2;
    sidx0[gbase + rr] = idx0[gbase + tg2];
    sidx1[gbase + rr] = idx1[gbase + tg2];
  }
}

// ---------------------------------------------------------------------------
// k3 v2: exact cumsum priorities, block-parallel. One BLOCK per (g,e):
// 128 blocks x 256 threads. Each thread counts matches in its 16 consecutive
// sorted positions; Hillis-Steele block scan gives exclusive offsets; second
// pass assigns priorities (k=0 stream, then k=1 continuing the count —
// identical integers to the sequential ballot scan).
// ---------------------------------------------------------------------------
__global__ __launch_bounds__(256) void k3_prio(
    const int* __restrict__ sidx0, const int* __restrict__ sidx1,
    const int* __restrict__ perm,
    int* __restrict__ prio0, int* __restrict__ prio1, int* __restrict__ cntge)
{
  __shared__ int sc[256];
  const int tid = threadIdx.x;
  const int g = blockIdx.x >> 6;
  const int e = blockIdx.x & 63;
  const size_t gbase = (size_t)g * Tn;
  const int p0 = tid * 16;

  int base = 0;
  #pragma unroll
  for (int ph = 0; ph < 2; ++ph) {
    const int* __restrict__ sidx = ph ? sidx1 : sidx0;
    int* __restrict__ prio = ph ? prio1 : prio0;

    int loc[16];
    const int4* s4 = (const int4*)(sidx + gbase + p0);
    #pragma unroll
    for (int u = 0; u < 4; ++u) {
      int4 v = s4[u];
      loc[u * 4 + 0] = v.x; loc[u * 4 + 1] = v.y;
      loc[u * 4 + 2] = v.z; loc[u * 4 + 3] = v.w;
    }
    int cntl = 0;
    #pragma unroll
    for (int k = 0; k < 16; ++k) cntl += (loc[k] == e);

    __syncthreads();                   // protect sc reuse across phases
    sc[tid] = cntl;
    __syncthreads();
    #pragma unroll
    for (int off = 1; off < 256; off <<= 1) {
      int v = (tid >= off) ? sc[tid - off] : 0;
      __syncthreads();
      sc[tid] += v;
      __syncthreads();
    }
    int pr = base + sc[tid] - cntl;    // exclusive prefix + phase base
    int total = sc[255];
    #pragma unroll
    for (int k = 0; k < 16; ++k) {
      if (loc[k] == e) {
        prio[gbase + perm[gbase + p0 + k]] = pr;
        ++pr;
      }
    }
    base += total;
  }
  if (tid == 0) cntge[g * En + e] = base;
}

// ---------------------------------------------------------------------------
// k5a: per-group partials. Block g: zpart = sum(dlogz2[g]), auxpart =
// sum_e( cntge[g][e] * sum_b partial[b][e] ). Deterministic fixed trees.
// ---------------------------------------------------------------------------
__global__ __launch_bounds__(256) void k5a(
    const double* __restrict__ dlogz2, const double* __restrict__ partial,
    const int* __restrict__ cntge, double* __restrict__ gpart)
{
  __shared__ double red[256];
  const int g = blockIdx.x;
  const int tid = threadIdx.x;

  double z = 0.0;
  for (int i = tid; i < Tn; i += 256) z += dlogz2[(size_t)g * Tn + i];
  red[tid] = z; __syncthreads();
  for (int s = 128; s; s >>= 1) { if (tid < s) red[tid] += red[tid + s]; __syncthreads(); }
  if (tid == 0) gpart[g * 2 + 0] = red[0];
  __syncthreads();

  // sum partial over this group's 256 k1-blocks (coalesced 2KB per iter)
  const int q = tid >> 6, e = tid & 63;
  double s = 0.0;
  for (int i = 0; i < 64; ++i) {
    int b = g * 256 + i * 4 + q;
    s += partial[(size_t)b * 64 + e];
  }
  red[tid] = s; __syncthreads();
  if (tid < 64) {
    double sp = red[tid] + red[64 + tid] + red[128 + tid] + red[192 + tid];
    red[tid] = sp * (double)cntge[g * En + tid];
  }
  __syncthreads();
  for (int st = 32; st; st >>= 1) { if (tid < st) red[tid] += red[tid + st]; __syncthreads(); }
  if (tid == 0) gpart[g * 2 + 1] = red[0];
}

// ---------------------------------------------------------------------------
// k6 v2: sparse scatter only (zeros already written by k1). One thread per
// token writes its <=2 dispatch ones + <=2 combine gates. Thread 0 of
// block 0 finalizes the two scalar losses.
// ---------------------------------------------------------------------------
__global__ __launch_bounds__(256) void k6_fill(
    const int* __restrict__ idx0, const int* __restrict__ idx1,
    const int* __restrict__ prio0, const int* __restrict__ prio1,
    const float* __restrict__ g0f, const float* __restrict__ g1f,
    const double* __restrict__ gpart,
    float* __restrict__ out)
{
  const int t = blockIdx.x * 256 + threadIdx.x;    // 0..GT-1
  if (t < (int)GT) {
    const size_t gt = (size_t)t;
    const int e0 = idx0[gt], e1 = idx1[gt];
    const int p0 = prio0[gt], p1 = prio1[gt];
    const size_t slab = gt * (size_t)(En * CAPn);
    if (p0 < CAPn) {
      size_t n = slab + e0 * CAPn + p0;
      out[n] = 1.0f;
      out[GTEC + n] = g0f[gt];
    }
    if (p1 < CAPn) {
      size_t n = slab + e1 * CAPn + p1;
      out[n] = 1.0f;
      out[GTEC + n] = g1f[gt];
    }
  }
  if (t == 0) {
    double aux = (gpart[1] + gpart[3]) * (double)En /
                 ((double)Gn * (double)Tn * (double)Tn);
    double z   = (gpart[0] + gpart[2]) / (double)GT;
    out[GTEC * 2]     = (float)aux;
    out[GTEC * 2 + 1] = (float)z;
  }
}

// ---------------------------------------------------------------------------
extern "C" void kernel_launch(void* const* d_in, const int* in_sizes, int n_in,
                              void* d_out, int out_size, void* d_ws, size_t ws_size,
                              hipStream_t stream)
{
  (void)in_sizes; (void)n_in; (void)out_size; (void)ws_size;
  const float* X  = (const float*)d_in[0];   // [G,T,H]
  const float* W  = (const float*)d_in[1];   // [H,E]
  const float* Bv = (const float*)d_in[2];   // [E]
  float* out = (float*)d_out;

  char* ws = (char*)d_ws;
  size_t off = 0;
  auto carve = [&](size_t bytes) -> void* {
    void* p = ws + off;
    off += (bytes + 255) & ~(size_t)255;
    return p;
  };
  double* rowmap  = (double*)carve(64 * 4 * 8);
  double* colmap  = (double*)carve(64 * 4 * 8);
  double* dkey    = (double*)carve(GT * 8);
  double* dlogz2  = (double*)carve(GT * 8);
  double* partial = (double*)carve((size_t)512 * 64 * 8);  // 256 KB
  double* gpart   = (double*)carve(4 * 8);
  int* idx0  = (int*)carve(GT * 4);
  int* idx1  = (int*)carve(GT * 4);
  float* g0f = (float*)carve(GT * 4);
  float* g1f = (float*)carve(GT * 4);
  int* perm  = (int*)carve(GT * 4);
  int* sidx0 = (int*)carve(GT * 4);
  int* sidx1 = (int*)carve(GT * 4);
  int* prio0 = (int*)carve(GT * 4);
  int* prio1 = (int*)carve(GT * 4);
  int* cntge = (int*)carve((size_t)Gn * En * 4);

  k0_probe<<<1, 64, 0, stream>>>(rowmap, colmap);
  k1_gemm<<<512, 512, 0, stream>>>(X, W, Bv, rowmap, colmap, dkey, dlogz2,
                                   idx0, idx1, g0f, g1f, partial, out);
  k2_rank<<<Gn * 128, 256, 0, stream>>>(dkey, idx0, idx1, perm, sidx0, sidx1);
  k3_prio<<<Gn * En, 256, 0, stream>>>(sidx0, sidx1, perm, prio0, prio1, cntge);
  k5a<<<Gn, 256, 0, stream>>>(dlogz2, partial, cntge, gpart);
  k6_fill<<<(int)(GT / 256), 256, 0, stream>>>(idx0, idx1, prio0, prio1,
                                               g0f, g1f, gpart, out);
}

// Round 13
// 155.530 us; speedup vs baseline: 1.1280x; 1.1280x over previous
//
#include <hip/hip_runtime.h>
#include <cstdint>
#include <cstddef>

static constexpr int Gn = 2;
static constexpr int Tn = 4096;
static constexpr int Hn = 2048;
static constexpr int En = 64;
static constexpr int CAPn = 128;
static constexpr size_t GT = (size_t)Gn * Tn;          // 8192
static constexpr size_t GTEC = GT * En * CAPn;         // 67,108,864
static constexpr size_t GTEC4 = GTEC / 4;              // float4 units

typedef float  f4v __attribute__((ext_vector_type(4)));  // NT-store vec
typedef double d4v __attribute__((ext_vector_type(4)));  // MFMA f64 acc

// ---------------------------------------------------------------------------
// Wave-level (64 lanes = 64 experts) softmax + top-2 + z-loss term, all f64.
// Returns p (this lane's expert probability) for the caller's aux-loss sum.
// Tie-breaking on equal probs: lower expert index wins (matches lax.top_k).
// ---------------------------------------------------------------------------
__device__ inline double wave_softmax_topk(
    double logit, int g, int t,
    double* __restrict__ dkey, double* __restrict__ dlogz2,
    int* __restrict__ idx0, int* __restrict__ idx1,
    float* __restrict__ g0f, float* __restrict__ g1f)
{
  const int e = threadIdx.x & 63;
  double m = logit;
  #pragma unroll
  for (int off = 32; off; off >>= 1) {
    double o = __shfl_xor(m, off);
    m = o > m ? o : m;
  }
  double ex = exp(logit - m);
  double s = ex;
  #pragma unroll
  for (int off = 32; off; off >>= 1) s += __shfl_xor(s, off);
  double p = ex / s;
  size_t gt = (size_t)g * Tn + t;

  // top-1 (value, index) with lower-index tie-break
  double bp = p; int bi = e;
  #pragma unroll
  for (int off = 32; off; off >>= 1) {
    double op = __shfl_xor(bp, off);
    int    oi = __shfl_xor(bi, off);
    if (op > bp || (op == bp && oi < bi)) { bp = op; bi = oi; }
  }
  // top-2: mask out top-1 lane
  double q = (e == bi) ? -1.0 : p;
  double bp2 = q; int bi2 = e;
  #pragma unroll
  for (int off = 32; off; off >>= 1) {
    double op = __shfl_xor(bp2, off);
    int    oi = __shfl_xor(bi2, off);
    if (op > bp2 || (op == bp2 && oi < bi2)) { bp2 = op; bi2 = oi; }
  }
  if (e == 0) {
    dkey[gt] = bp;                       // sort key = top-1 gate (f64)
    double lz = m + log(s);              // logsumexp
    dlogz2[gt] = lz * lz;
    idx0[gt] = bi;  idx1[gt] = bi2;
    g0f[gt] = (float)bp;  g1f[gt] = (float)bp2;
  }
  return p;
}

// ---------------------------------------------------------------------------
// k0_probe: empirically determine the f64 MFMA D-fragment layout.
// Probe 1: A[i][k]=i, B=1  => D[i][j] = 4i  -> rowmap[lane][r] = 4*row.
// Probe 2: A=1, B[k][j]=j  => D[i][j] = 4j  -> colmap[lane][r] = 4*col.
// Integer-exact in f64; makes k1 correct under ANY D permutation.
// ---------------------------------------------------------------------------
__global__ __launch_bounds__(64) void k0_probe(
    double* __restrict__ rowmap, double* __restrict__ colmap)
{
  const int lane = threadIdx.x & 63;
  const double ai = (double)(lane & 15);
  d4v accR = {0., 0., 0., 0.};
  d4v accC = {0., 0., 0., 0.};
  accR = __builtin_amdgcn_mfma_f64_16x16x4f64(ai, 1.0, accR, 0, 0, 0);
  accC = __builtin_amdgcn_mfma_f64_16x16x4f64(1.0, ai, accC, 0, 0, 0);
  #pragma unroll
  for (int r = 0; r < 4; ++r) {
    rowmap[lane * 4 + r] = accR[r];
    colmap[lane * 4 + r] = accC[r];
  }
}

// ---------------------------------------------------------------------------
// k1 v12: BLOCK-LEVEL role split, no cross-role barriers.
// Grid 1024 x 256 thr, fully co-resident (34 KB LDS -> 4 blocks/CU).
// EVEN blocks (cb=bid>>1): COMPUTE ONLY — R10's validated structure:
//   4 waves, wave w owns H-quarter w (512 h = 128 K-steps), 1-deep register
//   prefetch, f64-MFMA with probe-corrected D mapping, fixed-order H-sum,
//   softmax/top2 + psum partials. Zero stores in the instruction stream ->
//   load waitcnts never wait on store drain.
// ODD blocks (fb=bid>>1): FILL ONLY — 1 MiB of linear NT zero-stores into
//   the output (512 blocks x 65536 float4 = full 512 MiB). No loads, no
//   barriers; HBM write queue self-throttles. Fill and compute overlap
//   chip-wide with decoupled per-wave vmcnt streams.
// ---------------------------------------------------------------------------
__global__ __launch_bounds__(256, 4) void k1_gemm(
    const float* __restrict__ X, const float* __restrict__ W,
    const float* __restrict__ Bv,
    const double* __restrict__ rowmap, const double* __restrict__ colmap,
    double* __restrict__ dkey, double* __restrict__ dlogz2,
    int* __restrict__ idx0, int* __restrict__ idx1,
    float* __restrict__ g0f, float* __restrict__ g1f,
    double* __restrict__ partial, float* __restrict__ out)
{
  __shared__ double lred[4][16][64];               // 32 KB partial logits
  __shared__ double pred[4][64];                   // 2 KB psum partials
  const int tid  = threadIdx.x;
  const int bid  = blockIdx.x;

  if (bid & 1) {
    // ---------------- fill block: 65536 float4 zeros, linear ------------
    const size_t base = (size_t)(bid >> 1) * 65536;
    f4v* __restrict__ ob = (f4v*)out;
    const f4v zf = {0.f, 0.f, 0.f, 0.f};
    #pragma unroll 8
    for (int it = 0; it < 256; ++it) {
      __builtin_nontemporal_store(zf, &ob[base + (size_t)it * 256 + tid]);
    }
    return;
  }

  // ---------------- compute block ---------------------------------------
  const int cb   = bid >> 1;                       // 0..511
  const int lane = tid & 63;
  const int w    = tid >> 6;                       // H-quarter 0..3
  const int g    = cb >> 8;                        // 256 blocks per group
  const int tb   = (cb & 255) * 16;                // block's first token
  const size_t gt0 = (size_t)g * Tn + tb;

  const int tl = lane & 15;                        // i (A-row) / j (B-col)
  const int kl = lane >> 4;                        // k within K=4

  int rowm[4], colm[4];
  #pragma unroll
  for (int r = 0; r < 4; ++r) {
    rowm[r] = (int)(rowmap[lane * 4 + r] * 0.25 + 0.5);
    colm[r] = (int)(colmap[lane * 4 + r] * 0.25 + 0.5);
  }

  const float* __restrict__ xa = X + (gt0 + tl) * Hn + w * 512 + kl;
  const float* __restrict__ wb = W + (size_t)(w * 512 + kl) * En + tl;

  d4v acc0 = {0., 0., 0., 0.};
  d4v acc1 = {0., 0., 0., 0.};
  d4v acc2 = {0., 0., 0., 0.};
  d4v acc3 = {0., 0., 0., 0.};

  // prologue: load step 0
  float a_n = xa[0];
  float w0_n = wb[0], w1_n = wb[16], w2_n = wb[32], w3_n = wb[48];

  for (int k4 = 0; k4 < 128; ++k4) {
    double a  = (double)a_n;
    double b0 = (double)w0_n;
    double b1 = (double)w1_n;
    double b2 = (double)w2_n;
    double b3 = (double)w3_n;
    if (k4 < 127) {                                // prefetch next step
      a_n = xa[4 * (k4 + 1)];
      const float* wr = wb + (size_t)(4 * (k4 + 1)) * En;
      w0_n = wr[0]; w1_n = wr[16]; w2_n = wr[32]; w3_n = wr[48];
    }
    acc0 = __builtin_amdgcn_mfma_f64_16x16x4f64(a, b0, acc0, 0, 0, 0);
    acc1 = __builtin_amdgcn_mfma_f64_16x16x4f64(a, b1, acc1, 0, 0, 0);
    acc2 = __builtin_amdgcn_mfma_f64_16x16x4f64(a, b2, acc2, 0, 0, 0);
    acc3 = __builtin_amdgcn_mfma_f64_16x16x4f64(a, b3, acc3, 0, 0, 0);
  }

  // D[rowm[r]][colm[r] + 16*et] -> lred[w][token][expert] (probe-corrected)
  #pragma unroll
  for (int r = 0; r < 4; ++r) {
    lred[w][rowm[r]][colm[r]]      = acc0[r];
    lred[w][rowm[r]][16 + colm[r]] = acc1[r];
    lred[w][rowm[r]][32 + colm[r]] = acc2[r];
    lred[w][rowm[r]][48 + colm[r]] = acc3[r];
  }
  __syncthreads();

  // softmax/top2: wave w handles tokens 4w..4w+3; lane = expert.
  const double bv = (double)Bv[lane];
  double psum = 0.0;
  #pragma unroll
  for (int j = 0; j < 4; ++j) {
    int t = w * 4 + j;
    double full = lred[0][t][lane] + lred[1][t][lane]
                + lred[2][t][lane] + lred[3][t][lane] + bv;
    psum += wave_softmax_topk(full, g, tb + t,
                              dkey, dlogz2, idx0, idx1, g0f, g1f);
  }
  pred[w][lane] = psum;
  __syncthreads();
  if (tid < 64) {
    partial[(size_t)cb * 64 + tid] =
        pred[0][tid] + pred[1][tid] + pred[2][tid] + pred[3][tid];
  }
}

// ---------------------------------------------------------------------------
// k2: stable descending rank, parallelized. 256 blocks; each block ranks
// 32 tokens against all Tn keys (staged once in LDS); 8 threads per token
// each scan 512 keys via b128 reads; integer partials summed exactly.
// ---------------------------------------------------------------------------
__global__ __launch_bounds__(256) void k2_rank(
    const double* __restrict__ dkey,
    const int* __restrict__ idx0, const int* __restrict__ idx1,
    int* __restrict__ perm, int* __restrict__ sidx0, int* __restrict__ sidx1)
{
  __shared__ __align__(16) double keys[Tn];        // 32 KB
  __shared__ int rk[32][8];
  const int tid = threadIdx.x;
  const int bid = blockIdx.x;
  const int g    = bid >> 7;                       // 128 blocks per group
  const int part = bid & 127;                      // 32 tokens per block
  const size_t gbase = (size_t)g * Tn;
  for (int i = tid; i < Tn; i += 256) keys[i] = dkey[gbase + i];
  __syncthreads();

  const int tl = tid >> 3;                         // token-local 0..31
  const int q  = tid & 7;                          // scan segment 0..7
  const int tg = part * 32 + tl;
  const double k = keys[tg];
  int r = 0;
  #pragma unroll 4
  for (int j2 = q * 512; j2 < q * 512 + 512; j2 += 2) {
    double2 kj = *(const double2*)&keys[j2];
    r += (kj.x > k) || (kj.x == k && (j2     < tg));
    r += (kj.y > k) || (kj.y == k && (j2 + 1 < tg));
  }
  rk[tl][q] = r;
  __syncthreads();
  if (tid < 32) {
    const int tg2 = part * 32 + tid;
    int rr = 0;
    #pragma unroll
    for (int u = 0; u < 8; ++u) rr += rk[tid][u];
    perm[gbase + rr]  = tg2;
    sidx0[gbase + rr] = idx0[gbase + tg2];
    sidx1[gbase + rr] = idx1[gbase + tg2];
  }
}

// ---------------------------------------------------------------------------
// k3 v2: exact cumsum priorities, block-parallel. One BLOCK per (g,e):
// 128 blocks x 256 threads. Each thread counts matches in its 16 consecutive
// sorted positions; Hillis-Steele block scan gives exclusive offsets; second
// pass assigns priorities (k=0 stream, then k=1 continuing the count —
// identical integers to the sequential ballot scan).
// ---------------------------------------------------------------------------
__global__ __launch_bounds__(256) void k3_prio(
    const int* __restrict__ sidx0, const int* __restrict__ sidx1,
    const int* __restrict__ perm,
    int* __restrict__ prio0, int* __restrict__ prio1, int* __restrict__ cntge)
{
  __shared__ int sc[256];
  const int tid = threadIdx.x;
  const int g = blockIdx.x >> 6;
  const int e = blockIdx.x & 63;
  const size_t gbase = (size_t)g * Tn;
  const int p0 = tid * 16;

  int base = 0;
  #pragma unroll
  for (int ph = 0; ph < 2; ++ph) {
    const int* __restrict__ sidx = ph ? sidx1 : sidx0;
    int* __restrict__ prio = ph ? prio1 : prio0;

    int loc[16];
    const int4* s4 = (const int4*)(sidx + gbase + p0);
    #pragma unroll
    for (int u = 0; u < 4; ++u) {
      int4 v = s4[u];
      loc[u * 4 + 0] = v.x; loc[u * 4 + 1] = v.y;
      loc[u * 4 + 2] = v.z; loc[u * 4 + 3] = v.w;
    }
    int cntl = 0;
    #pragma unroll
    for (int k = 0; k < 16; ++k) cntl += (loc[k] == e);

    __syncthreads();                   // protect sc reuse across phases
    sc[tid] = cntl;
    __syncthreads();
    #pragma unroll
    for (int off = 1; off < 256; off <<= 1) {
      int v = (tid >= off) ? sc[tid - off] : 0;
      __syncthreads();
      sc[tid] += v;
      __syncthreads();
    }
    int pr = base + sc[tid] - cntl;    // exclusive prefix + phase base
    int total = sc[255];
    #pragma unroll
    for (int k = 0; k < 16; ++k) {
      if (loc[k] == e) {
        prio[gbase + perm[gbase + p0 + k]] = pr;
        ++pr;
      }
    }
    base += total;
  }
  if (tid == 0) cntge[g * En + e] = base;
}

// ---------------------------------------------------------------------------
// k5a: per-group partials. Block g: zpart = sum(dlogz2[g]), auxpart =
// sum_e( cntge[g][e] * sum_b partial[b][e] ). Deterministic fixed trees.
// ---------------------------------------------------------------------------
__global__ __launch_bounds__(256) void k5a(
    const double* __restrict__ dlogz2, const double* __restrict__ partial,
    const int* __restrict__ cntge, double* __restrict__ gpart)
{
  __shared__ double red[256];
  const int g = blockIdx.x;
  const int tid = threadIdx.x;

  double z = 0.0;
  for (int i = tid; i < Tn; i += 256) z += dlogz2[(size_t)g * Tn + i];
  red[tid] = z; __syncthreads();
  for (int s = 128; s; s >>= 1) { if (tid < s) red[tid] += red[tid + s]; __syncthreads(); }
  if (tid == 0) gpart[g * 2 + 0] = red[0];
  __syncthreads();

  // sum partial over this group's 256 compute blocks (coalesced 2KB/iter)
  const int q = tid >> 6, e = tid & 63;
  double s = 0.0;
  for (int i = 0; i < 64; ++i) {
    int b = g * 256 + i * 4 + q;
    s += partial[(size_t)b * 64 + e];
  }
  red[tid] = s; __syncthreads();
  if (tid < 64) {
    double sp = red[tid] + red[64 + tid] + red[128 + tid] + red[192 + tid];
    red[tid] = sp * (double)cntge[g * En + tid];
  }
  __syncthreads();
  for (int st = 32; st; st >>= 1) { if (tid < st) red[tid] += red[tid + st]; __syncthreads(); }
  if (tid == 0) gpart[g * 2 + 1] = red[0];
}

// ---------------------------------------------------------------------------
// k6 v2: sparse scatter only (zeros already written by k1's fill blocks).
// One thread per token writes its <=2 dispatch ones + <=2 combine gates.
// Thread 0 of block 0 finalizes the two scalar losses.
// ---------------------------------------------------------------------------
__global__ __launch_bounds__(256) void k6_fill(
    const int* __restrict__ idx0, const int* __restrict__ idx1,
    const int* __restrict__ prio0, const int* __restrict__ prio1,
    const float* __restrict__ g0f, const float* __restrict__ g1f,
    const double* __restrict__ gpart,
    float* __restrict__ out)
{
  const int t = blockIdx.x * 256 + threadIdx.x;    // 0..GT-1
  if (t < (int)GT) {
    const size_t gt = (size_t)t;
    const int e0 = idx0[gt], e1 = idx1[gt];
    const int p0 = prio0[gt], p1 = prio1[gt];
    const size_t slab = gt * (size_t)(En * CAPn);
    if (p0 < CAPn) {
      size_t n = slab + e0 * CAPn + p0;
      out[n] = 1.0f;
      out[GTEC + n] = g0f[gt];
    }
    if (p1 < CAPn) {
      size_t n = slab + e1 * CAPn + p1;
      out[n] = 1.0f;
      out[GTEC + n] = g1f[gt];
    }
  }
  if (t == 0) {
    double aux = (gpart[1] + gpart[3]) * (double)En /
                 ((double)Gn * (double)Tn * (double)Tn);
    double z   = (gpart[0] + gpart[2]) / (double)GT;
    out[GTEC * 2]     = (float)aux;
    out[GTEC * 2 + 1] = (float)z;
  }
}

// ---------------------------------------------------------------------------
extern "C" void kernel_launch(void* const* d_in, const int* in_sizes, int n_in,
                              void* d_out, int out_size, void* d_ws, size_t ws_size,
                              hipStream_t stream)
{
  (void)in_sizes; (void)n_in; (void)out_size; (void)ws_size;
  const float* X  = (const float*)d_in[0];   // [G,T,H]
  const float* W  = (const float*)d_in[1];   // [H,E]
  const float* Bv = (const float*)d_in[2];   // [E]
  float* out = (float*)d_out;

  char* ws = (char*)d_ws;
  size_t off = 0;
  auto carve = [&](size_t bytes) -> void* {
    void* p = ws + off;
    off += (bytes + 255) & ~(size_t)255;
    return p;
  };
  double* rowmap  = (double*)carve(64 * 4 * 8);
  double* colmap  = (double*)carve(64 * 4 * 8);
  double* dkey    = (double*)carve(GT * 8);
  double* dlogz2  = (double*)carve(GT * 8);
  double* partial = (double*)carve((size_t)512 * 64 * 8);  // 256 KB
  double* gpart   = (double*)carve(4 * 8);
  int* idx0  = (int*)carve(GT * 4);
  int* idx1  = (int*)carve(GT * 4);
  float* g0f = (float*)carve(GT * 4);
  float* g1f = (float*)carve(GT * 4);
  int* perm  = (int*)carve(GT * 4);
  int* sidx0 = (int*)carve(GT * 4);
  int* sidx1 = (int*)carve(GT * 4);
  int* prio0 = (int*)carve(GT * 4);
  int* prio1 = (int*)carve(GT * 4);
  int* cntge = (int*)carve((size_t)Gn * En * 4);

  k0_probe<<<1, 64, 0, stream>>>(rowmap, colmap);
  k1_gemm<<<1024, 256, 0, stream>>>(X, W, Bv, rowmap, colmap, dkey, dlogz2,
                                    idx0, idx1, g0f, g1f, partial, out);
  k2_rank<<<Gn * 128, 256, 0, stream>>>(dkey, idx0, idx1, perm, sidx0, sidx1);
  k3_prio<<<Gn * En, 256, 0, stream>>>(sidx0, sidx1, perm, prio0, prio1, cntge);
  k5a<<<Gn, 256, 0, stream>>>(dlogz2, partial, cntge, gpart);
  k6_fill<<<(int)(GT / 256), 256, 0, stream>>>(idx0, idx1, prio0, prio1,
                                               g0f, g1f, gpart, out);
}